// Round 1
// 49182.977 us; speedup vs baseline: 1.3162x; 1.3162x over previous
//
#include <hip/hip_runtime.h>
#include <math.h>

typedef long long i64;

// ---------------------------------------------------------------------------
// Reduction helpers (256-thread block = 4 waves of 64)
// ---------------------------------------------------------------------------
__device__ __forceinline__ float waveReduceSum(float v){
#pragma unroll
  for(int o=32;o>0;o>>=1) v += __shfl_down(v,o,64);
  return v;
}
__device__ __forceinline__ float waveReduceMin(float v){
#pragma unroll
  for(int o=32;o>0;o>>=1) v = fminf(v, __shfl_down(v,o,64));
  return v;
}
__device__ __forceinline__ float waveReduceMax(float v){
#pragma unroll
  for(int o=32;o>0;o>>=1) v = fmaxf(v, __shfl_down(v,o,64));
  return v;
}
__device__ __forceinline__ float blockReduceSum256(float val, float* red){
  __syncthreads();
  val = waveReduceSum(val);
  if((threadIdx.x&63)==0) red[threadIdx.x>>6]=val;
  __syncthreads();
  return red[0]+red[1]+red[2]+red[3];
}
__device__ __forceinline__ float blockReduceMin256(float val, float* red){
  __syncthreads();
  val = waveReduceMin(val);
  if((threadIdx.x&63)==0) red[threadIdx.x>>6]=val;
  __syncthreads();
  return fminf(fminf(red[0],red[1]),fminf(red[2],red[3]));
}
__device__ __forceinline__ float blockReduceMax256(float val, float* red){
  __syncthreads();
  val = waveReduceMax(val);
  if((threadIdx.x&63)==0) red[threadIdx.x>>6]=val;
  __syncthreads();
  return fmaxf(fmaxf(red[0],red[1]),fmaxf(red[2],red[3]));
}

// ---------------------------------------------------------------------------
// Generic strided 2D copy: dst[doff + r*dld + c] = src[soff + r*sld + c]
// ---------------------------------------------------------------------------
__global__ __launch_bounds__(256) void fd_copyblk(
    float* __restrict__ dst, int dld, i64 doff,
    const float* __restrict__ src, int sld, i64 soff,
    int rows, int cols)
{
  i64 tot = (i64)rows*cols;
  for(i64 id = (i64)blockIdx.x*256 + threadIdx.x; id < tot; id += (i64)gridDim.x*256){
    int r = (int)(id / cols), c = (int)(id % cols);
    dst[doff + (i64)r*dld + c] = src[soff + (i64)r*sld + c];
  }
}

// ---------------------------------------------------------------------------
// Column scale: out (rows x 128) = in * diag(w)
// ---------------------------------------------------------------------------
__global__ __launch_bounds__(256) void fd_colscale(
    const float* __restrict__ in, const float* __restrict__ w,
    float* __restrict__ out, int rows)
{
  int tot = rows*128;
  for(int id = blockIdx.x*256 + threadIdx.x; id < tot; id += gridDim.x*256)
    out[id] = in[id] * w[id & 127];
}

// ---------------------------------------------------------------------------
// Generic fp32 GEMM: C = alpha*op(A)op(B) [+C if betaone] [+bias bcast over rows]
// tA: A stored K x M (row-major);  else M x K.  tB: B stored N x K; else K x N.
// grid = (M/64, N/64, kchunks). useAtomic -> atomicAdd into C (pre-zeroed).
// ---------------------------------------------------------------------------
__global__ __launch_bounds__(256) void fd_gemm(
    const float* __restrict__ A, const float* __restrict__ B,
    float* __restrict__ C, const float* __restrict__ bias,
    int M, int N, int K, int lda, int ldb, int ldc,
    int tA, int tB, float alpha, int betaone, int useAtomic)
{
  __shared__ float As[16][68];
  __shared__ float Bs[16][68];
  int bm = blockIdx.x*64, bn = blockIdx.y*64;
  int kchunk = K / gridDim.z;
  int k0 = blockIdx.z * kchunk;
  int tn = threadIdx.x & 15, tm = threadIdx.x >> 4;
  float acc[4][4] = {{0.f}};
  for(int kt = k0; kt < k0 + kchunk; kt += 16){
    if(tA){
      for(int l=threadIdx.x; l<1024; l+=256){ int kk=l>>6, mm=l&63;
        As[kk][mm] = A[(i64)(kt+kk)*lda + bm+mm]; }
    }else{
      for(int l=threadIdx.x; l<1024; l+=256){ int mm=l>>4, kk=l&15;
        As[kk][mm] = A[(i64)(bm+mm)*lda + kt+kk]; }
    }
    if(tB){
      for(int l=threadIdx.x; l<1024; l+=256){ int nn=l>>4, kk=l&15;
        Bs[kk][nn] = B[(i64)(bn+nn)*ldb + kt+kk]; }
    }else{
      for(int l=threadIdx.x; l<1024; l+=256){ int kk=l>>6, nn=l&63;
        Bs[kk][nn] = B[(i64)(kt+kk)*ldb + bn+nn]; }
    }
    __syncthreads();
#pragma unroll
    for(int kk=0; kk<16; kk++){
      float a[4], b[4];
#pragma unroll
      for(int i=0;i<4;i++){ a[i]=As[kk][tm*4+i]; b[i]=Bs[kk][tn*4+i]; }
#pragma unroll
      for(int i=0;i<4;i++)
#pragma unroll
        for(int j=0;j<4;j++) acc[i][j] += a[i]*b[j];
    }
    __syncthreads();
  }
#pragma unroll
  for(int i=0;i<4;i++){
    int row = bm + tm*4 + i;
#pragma unroll
    for(int j=0;j<4;j++){
      int col = bn + tn*4 + j;
      i64 idx = (i64)row*ldc + col;
      float v = alpha*acc[i][j];
      if(useAtomic){ atomicAdd(&C[idx], v); }
      else{
        if(betaone) v += C[idx];
        if(bias)    v += bias[col];
        C[idx] = v;
      }
    }
  }
}

// ---------------------------------------------------------------------------
// Cholesky of a 128x128 SPD block (packed-lower in LDS), regularized.
// Body shared by single and batched (x2) kernels.
// ---------------------------------------------------------------------------
__device__ __forceinline__ void chol128_body(
    const float* __restrict__ G, int gld, i64 goff,
    float* __restrict__ L, int lld, i64 loff,
    float* P, float* colv, float* sc)
{
  int t = threadIdx.x;
  for(int i=t;i<128;i+=256){
    int base = i*(i+1)/2;
    for(int j=0;j<=i;j++) P[base+j] = G[goff + (i64)i*gld + j];
  }
  __syncthreads();
  if(t==0){
    float m=0.f;
    for(int i=0;i<128;i++){ float dd=P[i*(i+1)/2+i]; if(dd>m) m=dd; }
    if(!(m>0.f)) m = 1e-20f;
    sc[0] = m*4e-6f;   // diagonal regularization
    sc[1] = m*1e-8f;   // pivot floor
  }
  __syncthreads();
  float reg = sc[0], flo = sc[1];
  for(int i=t;i<128;i+=256) P[i*(i+1)/2+i] += reg;
  __syncthreads();
  for(int j=0;j<128;j++){
    int jb = j*(j+1)/2;
    if(t==0){
      float dd = fmaxf(P[jb+j], flo);
      float piv = sqrtf(dd);
      P[jb+j] = piv;
      colv[j] = piv;
    }
    __syncthreads();
    float pr = 1.f/colv[j];
    for(int i=j+1+t; i<128; i+=256){
      int base = i*(i+1)/2;
      float v = P[base+j]*pr;
      P[base+j] = v;
      colv[i] = v;
    }
    __syncthreads();
    for(int i=j+1+t; i<128; i+=256){
      int base = i*(i+1)/2;
      float ci = colv[i];
      for(int kx=j+1; kx<=i; kx++) P[base+kx] -= ci*colv[kx];
    }
    __syncthreads();
  }
  for(int i=t;i<128;i+=256){
    int base = i*(i+1)/2;
    for(int j=0;j<=i;j++)      L[loff + (i64)i*lld + j] = P[base+j];
    for(int j=i+1;j<128;j++)   L[loff + (i64)i*lld + j] = 0.f;
  }
}

__global__ __launch_bounds__(256) void fd_chol128(
    const float* __restrict__ G, int gld, i64 goff,
    float* __restrict__ L, int lld, i64 loff)
{
  __shared__ float P[8256];
  __shared__ float colv[128];
  __shared__ float sc[2];
  chol128_body(G,gld,goff,L,lld,loff,P,colv,sc);
}

// batched pair (independent x-side / y-side run on 2 concurrent blocks)
__global__ __launch_bounds__(256) void fd_chol128x2(
    const float* __restrict__ Ga, int glda, i64 goffa,
    float* __restrict__ La, int llda, i64 loffa,
    const float* __restrict__ Gb, int gldb, i64 goffb,
    float* __restrict__ Lb, int lldb, i64 loffb)
{
  __shared__ float P[8256];
  __shared__ float colv[128];
  __shared__ float sc[2];
  if(blockIdx.x==0) chol128_body(Ga,glda,goffa,La,llda,loffa,P,colv,sc);
  else              chol128_body(Gb,gldb,goffb,Lb,lldb,loffb,P,colv,sc);
}

// ---------------------------------------------------------------------------
// X = (L^T)^{-1} (upper 128x128, dense row-major). Thread k solves column k.
// ---------------------------------------------------------------------------
__device__ __forceinline__ void trinv128_body(
    const float* __restrict__ L, int lld, i64 loff, float* __restrict__ X,
    float* Ls /*128*129*/)
{
  int k = threadIdx.x;
  for(int idx=k; idx<16384; idx+=128){
    int i = idx >> 7, j = idx & 127;
    Ls[i*129+j] = L[loff + (i64)i*lld + j];
  }
  __syncthreads();
  for(int i=k+1;i<128;i++) X[(i64)i*128 + k] = 0.f;
  X[(i64)k*128 + k] = 1.f / Ls[k*129+k];
  for(int i=k-1;i>=0;i--){
    float s = 0.f;
    for(int j=i+1;j<=k;j++) s += Ls[j*129+i] * X[(i64)j*128 + k];
    X[(i64)i*128 + k] = -s / Ls[i*129+i];
  }
}

__global__ __launch_bounds__(128) void fd_trinv128(
    const float* __restrict__ L, int lld, i64 loff, float* __restrict__ X)
{
  __shared__ float Ls[128*129];
  trinv128_body(L,lld,loff,X,Ls);
}

__global__ __launch_bounds__(128) void fd_trinv128x2(
    const float* __restrict__ La, int llda, i64 loffa, float* __restrict__ Xa,
    const float* __restrict__ Lb, int lldb, i64 loffb, float* __restrict__ Xb)
{
  __shared__ float Ls[128*129];
  if(blockIdx.x==0) trinv128_body(La,llda,loffa,Xa,Ls);
  else              trinv128_body(Lb,lldb,loffb,Xb,Ls);
}

// ---------------------------------------------------------------------------
// Householder tridiagonalization of symmetric 256x256 A, fully in LDS.
// v2: 16B-aligned zero-padded packed-lower rows -> float4 (ds_read_b128)
//     row-dots and rank-2 update; column contributions computed by a
//     wave-split pass (lane L owns output cols 4L..4L+3, one coalesced
//     b128 read per trailing row) reduced through a small LDS scratch.
// Identical algebra to v1, different summation order only.
// ---------------------------------------------------------------------------
__global__ __launch_bounds__(256) void fd_tridiag(
    const float* __restrict__ A, float* __restrict__ dT,
    float* __restrict__ eT, float* __restrict__ Vh)
{
  const int n = 256;
  // padded packed lower: row i at 4*ceil((i+1)/4)-granular base, pads == 0.
  // total = 33280 floats = 133.1 KB (<160 KB)
  __shared__ __align__(16) float P[33280];
  __shared__ __align__(16) float v[256];
  __shared__ __align__(16) float w[256];
  __shared__ __align__(16) float colp[1024];   // per-wave column partials
  __shared__ int   ib4[256];                   // row base in float4 units
  __shared__ float red[8];
  int t = threadIdx.x;
  int L = t & 63, wv = t >> 6;
  {
    // base_i/4 = 2a(a+1)+b(a+1) = (a+1)(2a+b),  a=i>>2, b=i&3
    int a = t>>2, b = t&3;
    ib4[t] = (a+1)*(2*a+b);
  }
  for(int idx=t; idx<33280; idx+=256) P[idx] = 0.f;   // pads must stay 0
  __syncthreads();
  for(int i=0;i<n;i++){
    int base = ib4[i]<<2;
    for(int j=t;j<=i;j+=256) P[base+j] = A[(i64)i*n + j];
  }
  __syncthreads();
  int b4t = ib4[t];
  int bt  = b4t<<2;
  const float4* P4  = (const float4*)P;
  float4*       P4w = (float4*)P;
  const float4* V4  = (const float4*)v;
  const float4* W4  = (const float4*)w;
  float4*       C4  = (float4*)colp;
  int c0 = L<<2;

  for(int j=0;j<n-2;j++){
    float xi = (t>j)? P[bt + j] : 0.f;
    float nrm2 = blockReduceSum256(xi*xi, red);
    // all threads compute beta/vs redundantly (x0 is an LDS broadcast read)
    float x0 = P[(ib4[j+1]<<2) + j];
    float nr = sqrtf(nrm2);
    float beta = (x0>=0.f)? -nr : nr;
    float vn2 = 2.f*nrm2 - 2.f*beta*x0;
    float vs = (vn2>1e-30f)? rsqrtf(vn2) : 0.f;
    if(t==0) eT[j] = beta;
    float vt = (t>j)? (xi - ((t==j+1)? beta : 0.f))*vs : 0.f;
    v[t] = vt;
    Vh[(i64)j*n + t] = vt;
    __syncthreads();           // v ready

    // ---- u = A2 v ----
    // column contributions: u[c] += P[k][c]*v[k] for k>c (wave-split over k)
    float uc0=0.f, uc1=0.f, uc2=0.f, uc3=0.f;
#pragma unroll 2
    for(int k=j+1+wv; k<n; k+=4){
      int a = k>>2, b = k&3;
      int b4k = (a+1)*(2*a+b);          // SALU (k uniform per wave)
      float4 q = P4[b4k + L];           // coalesced b128; garbage beyond row masked
      float vk = v[k];
      uc0 += (c0+0 < k)? q.x*vk : 0.f;
      uc1 += (c0+1 < k)? q.y*vk : 0.f;
      uc2 += (c0+2 < k)? q.z*vk : 0.f;
      uc3 += (c0+3 < k)? q.w*vk : 0.f;
    }
    C4[(wv<<6) + L] = make_float4(uc0,uc1,uc2,uc3);

    // row contributions: u[t] += P[t][k]*v[k], k<=t (heads have v=0, pads are 0)
    float4 acc = make_float4(0.f,0.f,0.f,0.f);
    int qa = (j+1)>>2;
    if(t>j){
      int qe = t>>2;
      for(int q=qa; q<=qe; ++q){
        float4 pq = P4[b4t + q];
        float4 vq = V4[q];
        acc.x += pq.x*vq.x; acc.y += pq.y*vq.y;
        acc.z += pq.z*vq.z; acc.w += pq.w*vq.w;
      }
    }
    __syncthreads();           // colp ready
    float ucol = colp[t] + colp[256+t] + colp[512+t] + colp[768+t];
    float ut = (t>j)? (acc.x+acc.y+acc.z+acc.w + ucol) : 0.f;
    float gamma = blockReduceSum256(vt*ut, red);
    float wt = 2.f*ut - 2.f*gamma*vt;  // == 0 for t<=j (ut=0, vt=0)
    w[t] = wt;
    __syncthreads();           // w ready
    // rank-2 update of row t, cols j+1..t (vector blocks + scalar tail;
    // head cols <=j are no-ops since v=w=0 there; pads never written)
    if(t>j){
      int qv = (t>=3)? ((t-3)>>2) : -1;
      if(qv < qa) qv = qa-1;
      for(int q=qa; q<=qv; ++q){
        float4 pq = P4[b4t + q];
        float4 vq = V4[q];
        float4 wq = W4[q];
        pq.x -= vt*wq.x + wt*vq.x;
        pq.y -= vt*wq.y + wt*vq.y;
        pq.z -= vt*wq.z + wt*vq.z;
        pq.w -= vt*wq.w + wt*vq.w;
        P4w[b4t + q] = pq;
      }
      int ks = (qv+1)<<2; if(ks < j+1) ks = j+1;
      for(int k=ks; k<=t; ++k) P[bt+k] -= vt*w[k] + wt*v[k];
    }
    __syncthreads();
  }
  dT[t] = P[bt + t];
  if(t==0) eT[n-2] = P[(ib4[n-1]<<2) + (n-2)];
  if(t==1) eT[n-1] = 0.f;
}

// ---------------------------------------------------------------------------
// Bisection eigenvalues of tridiagonal T: lam[k] = k-th LARGEST, k=0..128.
// Sturm recurrence uses v_rcp_f32 (only the sign of q matters for counting);
// 34 iterations: interval width 2^-34 * range is below fp32 resolution.
// ---------------------------------------------------------------------------
__global__ __launch_bounds__(256) void fd_bisect(
    const float* __restrict__ dT, const float* __restrict__ eT,
    float* __restrict__ lam, float* __restrict__ wfx, float* __restrict__ wfy)
{
  __shared__ float d[256], e2[256], eabs[256];
  __shared__ float red[8];
  __shared__ float sgl, sgh, spm, sdel;
  int t = threadIdx.x;
  d[t] = dT[t];
  float ev = (t<255)? eT[t] : 0.f;
  e2[t] = ev*ev; eabs[t] = fabsf(ev);
  __syncthreads();
  float rr = ((t>0)? eabs[t-1] : 0.f) + eabs[t];
  float mn = blockReduceMin256(d[t]-rr, red);
  float mx = blockReduceMax256(d[t]+rr, red);
  if(t==0){
    sgl = mn; sgh = mx;
    float s = fmaxf(fabsf(mn), fabsf(mx));
    spm = fmaxf(1e-25f, 1e-12f*s);
  }
  __syncthreads();
  float glo=sgl, ghi=sgh, pivmin=spm;
  if(t<=128){
    int k = t;
    float lo=glo, hi=ghi;
    for(int it=0; it<34; it++){
      float mid = 0.5f*(lo+hi);
      int cnt=0;
      float q = d[0]-mid; if(q<0.f) cnt++;
      for(int i=1;i<256;i++){
        if(fabsf(q)<pivmin) q = -pivmin;
        q = (d[i]-mid) - e2[i-1]*__builtin_amdgcn_rcpf(q);
        if(q<0.f) cnt++;
      }
      if(cnt <= 255-k) lo=mid; else hi=mid;
    }
    lam[k] = lo;
  }
  __syncthreads();
  if(t==0) sdel = sqrtf(fmaxf(lam[128], 0.f));
  __syncthreads();
  if(t<128){
    float l = lam[t];
    float sg = sqrtf(fmaxf(l,0.f));
    float s2 = fmaxf(sg - sdel, 0.f);
    float s = sqrtf(s2);
    wfx[t] = (s2>0.f && l >1e-30f)? (s/l)  : 0.f;
    wfy[t] = (s2>0.f && sg>1e-30f)? (s/sg) : 0.f;
  }
}

// ---------------------------------------------------------------------------
// Inverse iteration (2 passes) for top-128 eigenvectors of tridiagonal T.
// ---------------------------------------------------------------------------
__global__ __launch_bounds__(128) void fd_invit(
    const float* __restrict__ dT, const float* __restrict__ eT,
    const float* __restrict__ lam, float* __restrict__ Ut,
    float* __restrict__ ud, float* __restrict__ ue, float* __restrict__ uf)
{
  __shared__ float d[256], e[256];
  int k = threadIdx.x;
  for(int i=k;i<256;i+=128){ d[i]=dT[i]; e[i]=(i<255)? eT[i] : 0.f; }
  __syncthreads();
  float scl = fmaxf(fabsf(lam[0]), 1e-20f);
  unsigned hh = (unsigned)k*2654435761u; hh ^= hh>>13; hh *= 1103515245u; hh ^= hh>>16;
  float pert = (float)(hh & 0xFFFFu) * (1.f/65536.f);
  float shift = lam[k] - scl*6e-7f*(0.25f + pert);
  float pivmin = 3e-7f*scl + 1e-30f;
#define AT(a,i) a[(i64)(i)*128 + k]
  for(int i=0;i<256;i++){
    unsigned z = ((unsigned)i*73856093u) ^ ((unsigned)k*19349663u);
    z ^= z>>13; z *= 2654435769u; z ^= z>>16;
    AT(Ut,i) = ((float)(z & 0xFFFFFFu) * (1.f/8388608.f)) - 1.f;
  }
  for(int pass=0; pass<2; pass++){
    float p = d[0]-shift, q = e[0], r = 0.f;
    for(int i=0;i<255;i++){
      float bel = e[i];
      float bn  = d[i+1]-shift;
      float cn  = (i+1<255)? e[i+1] : 0.f;
      float xi  = AT(Ut,i), xn = AT(Ut,i+1);
      if(fabsf(p) >= fabsf(bel)){
        float piv = (fabsf(p)<pivmin)? ((p<0.f)?-pivmin:pivmin) : p;
        float m = bel/piv;
        AT(ud,i)=piv; AT(ue,i)=q; AT(uf,i)=r;
        p = bn - m*q; q = cn - m*r; r = 0.f;
        AT(Ut,i+1) = xn - m*xi;
      } else {
        float piv = bel;
        float m = p/piv;
        AT(ud,i)=piv; AT(ue,i)=bn; AT(uf,i)=cn;
        p = q - m*bn; q = r - m*cn; r = 0.f;
        AT(Ut,i) = xn;
        AT(Ut,i+1) = xi - m*xn;
      }
    }
    {
      float piv = (fabsf(p)<pivmin)? ((p<0.f)?-pivmin:pivmin) : p;
      AT(ud,255)=piv;
    }
    float x1=0.f, x2=0.f, nrm2=0.f;
    for(int i=255;i>=0;i--){
      float s = AT(Ut,i);
      if(i<255) s -= AT(ue,i)*x1;
      if(i<254) s -= AT(uf,i)*x2;
      float x = s / AT(ud,i);
      x = fminf(fmaxf(x, -1e17f), 1e17f);
      AT(Ut,i) = x;
      x2=x1; x1=x;
      nrm2 += x*x;
    }
    float rn = rsqrtf(fmaxf(nrm2, 1e-30f));
    for(int i=0;i<256;i++) AT(Ut,i) *= rn;
  }
#undef AT
}

// ---------------------------------------------------------------------------
// Back-transform: Uout = Q * Uin, Q = H_0 ... H_253 (apply j=253..0).
// ---------------------------------------------------------------------------
__global__ __launch_bounds__(256) void fd_applyq(
    const float* __restrict__ Vh, const float* __restrict__ Uin,
    float* __restrict__ Uout)
{
  __shared__ float S[256][33];
  __shared__ float v[256];
  __shared__ float part[8][32];
  __shared__ float wc[32];
  int c = threadIdx.x & 31, g = threadIdx.x >> 5;   // 8 row-groups of 32
  int cb = blockIdx.x*32;
  for(int i=g*32; i<g*32+32; i++) S[i][c] = Uin[(i64)i*128 + cb + c];
  __syncthreads();
  for(int j=253;j>=0;j--){
    v[threadIdx.x] = Vh[(i64)j*256 + threadIdx.x];
    __syncthreads();
    float pd = 0.f;
    for(int i=g*32;i<g*32+32;i++) pd += v[i]*S[i][c];
    part[g][c] = pd;
    __syncthreads();
    if(g==0){
      float s=0.f;
#pragma unroll
      for(int gg=0;gg<8;gg++) s += part[gg][c];
      wc[c] = 2.f*s;
    }
    __syncthreads();
    float wv = wc[c];
    for(int i=g*32;i<g*32+32;i++) S[i][c] -= v[i]*wv;
    __syncthreads();
  }
  for(int i=g*32;i<g*32+32;i++) Uout[(i64)i*128 + cb + c] = S[i][c];
}

// ---------------------------------------------------------------------------
// Host driver
// ---------------------------------------------------------------------------
extern "C" void kernel_launch(void* const* d_in, const int* in_sizes, int n_in,
                              void* d_out, int out_size, void* d_ws, size_t ws_size,
                              hipStream_t stream)
{
  const float* x    = (const float*)d_in[0];   // 8192 x 1280
  const float* wgt  = (const float*)d_in[1];   // 5120 x 1280
  const float* bias = (const float*)d_in[2];   // 5120
  float* out = (float*)d_out;

  const int m = 8192, p = 5120, ldx = 1280, nb = 10;

  // ---- scratch layout: everything dead-before-final lives inside d_out ----
  float* ob = (float*)d_out;
  i64 o = 0;
  float* Cx  = ob+o; o += (i64)m*256;
  float* Cy  = ob+o; o += (i64)p*256;
  float* Gxx = ob+o; o += 65536;
  float* Gyy = ob+o; o += 65536;
  float* Lx  = ob+o; o += 65536;
  float* Ly  = ob+o; o += 65536;
  float* Km  = ob+o; o += 65536;
  float* Am  = ob+o; o += 65536;
  float* Vh  = ob+o; o += 65536;
  float* Ssx = ob+o; o += 16384;
  float* Ssy = ob+o; o += 16384;
  float* Xx  = ob+o; o += 16384;
  float* Xy  = ob+o; o += 16384;
  float* Xq  = ob+o; o += 16384;
  float* G1q = ob+o; o += 16384;
  float* dT  = ob+o; o += 256;
  float* eT  = ob+o; o += 256;
  float* lam = ob+o; o += 256;
  float* wfx = ob+o; o += 128;
  float* wfy = ob+o; o += 128;
  float* Ut  = ob+o; o += 32768;
  float* Uo1 = ob+o; o += 32768;
  float* Uo  = ob+o; o += 32768;
  float* Ub  = ob+o; o += 32768;
  float* Pm  = ob+o; o += 32768;
  float* Pf  = ob+o; o += 32768;
  float* Uf  = ob+o; o += 32768;
  float* Mx  = ob+o; o += 32768;
  float* My  = ob+o; o += 32768;
  float* iud = ob+o; o += 32768;
  float* iue = ob+o; o += 32768;
  float* iuf = ob+o; o += 32768;

  // Bx/By must survive into the final GEMM (which overwrites d_out) -> d_ws
  float* ws = (float*)d_ws;
  float* Bx = ws;                       // 8192 x 128
  float* By = ws + (i64)m*128;          // 5120 x 128
  (void)ws_size; (void)out_size; (void)n_in; (void)in_sizes;

  auto GEMM = [&](const float* A, const float* B, float* C, const float* bs,
                  int M,int N,int K,int lda,int ldb,int ldc,int tA,int tB,
                  float alpha,int betaone,int atom,int kz){
    dim3 g(M/64, N/64, kz);
    hipLaunchKernelGGL(fd_gemm, g, dim3(256), 0, stream,
                       A,B,C,bs,M,N,K,lda,ldb,ldc,tA,tB,alpha,betaone,atom);
  };
  auto COPY = [&](float* dst,int dld,i64 doff,const float* src,int sld,i64 soff,
                  int rows,int cols){
    i64 tot=(i64)rows*cols; int g=(int)((tot+255)/256); if(g>4096) g=4096;
    hipLaunchKernelGGL(fd_copyblk, dim3(g), dim3(256), 0, stream,
                       dst,dld,doff,src,sld,soff,rows,cols);
  };
  auto Z = [&](float* ptr, i64 elems){ hipMemsetAsync(ptr, 0, (size_t)elems*4, stream); };
  auto CHOL2 = [&](const float* Ga,int glda,i64 goffa, float* La,int llda,i64 loffa,
                   const float* Gb,int gldb,i64 goffb, float* Lb,int lldb,i64 loffb){
    hipLaunchKernelGGL(fd_chol128x2, dim3(2), dim3(256), 0, stream,
                       Ga,glda,goffa,La,llda,loffa, Gb,gldb,goffb,Lb,lldb,loffb);
  };
  auto TRINV2 = [&](const float* La,int llda,i64 loffa, float* Xa,
                    const float* Lb,int lldb,i64 loffb, float* Xb){
    hipLaunchKernelGGL(fd_trinv128x2, dim3(2), dim3(128), 0, stream,
                       La,llda,loffa,Xa, Lb,lldb,loffb,Xb);
  };

  for(int t=1;t<nb;t++){
    // ---- pack Cx = [Bx | x_t], Cy = [By | w_t] (step 1: Bx=x_0, By=w_0) ----
    if(t==1){ COPY(Cx,256,0, x,  ldx,0, m,128); COPY(Cy,256,0, wgt,ldx,0, p,128); }
    else    { COPY(Cx,256,0, Bx, 128,0, m,128); COPY(Cy,256,0, By, 128,0, p,128); }
    COPY(Cx,256,128, x,  ldx,(i64)t*128, m,128);
    COPY(Cy,256,128, wgt,ldx,(i64)t*128, p,128);

    // ---- Grams (split-K + atomics) ----
    Z(Gxx,65536); Z(Gyy,65536);
    GEMM(Cx,Cx,Gxx,nullptr, 256,256,8192, 256,256,256, 1,0, 1.f,0,1, 8);
    GEMM(Cy,Cy,Gyy,nullptr, 256,256,5120, 256,256,256, 1,0, 1.f,0,1, 5);

    // ---- blocked 256-Cholesky, x & y sides interleaved so the two
    //      independent chains run as batched 2-block launches ----
    Z(Lx,65536); Z(Ly,65536);
    CHOL2(Gxx,256,(i64)0, Lx,256,(i64)0,  Gyy,256,(i64)0, Ly,256,(i64)0);
    TRINV2(Lx,256,(i64)0, Xx,  Ly,256,(i64)0, Xy);
    GEMM(Gxx + (i64)128*256, Xx, Lx + (i64)128*256, nullptr,
         128,128,128, 256,128,256, 0,0, 1.f,0,0, 1);                 // L21x
    GEMM(Gyy + (i64)128*256, Xy, Ly + (i64)128*256, nullptr,
         128,128,128, 256,128,256, 0,0, 1.f,0,0, 1);                 // L21y
    COPY(Ssx,128,0, Gxx,256,(i64)128*256+128, 128,128);              // Sx = G22x
    COPY(Ssy,128,0, Gyy,256,(i64)128*256+128, 128,128);              // Sy = G22y
    GEMM(Lx + (i64)128*256, Lx + (i64)128*256, Ssx, nullptr,
         128,128,128, 256,256,128, 0,1, -1.f,1,0, 1);                // Sx -= L21x L21x^T
    GEMM(Ly + (i64)128*256, Ly + (i64)128*256, Ssy, nullptr,
         128,128,128, 256,256,128, 0,1, -1.f,1,0, 1);                // Sy -= L21y L21y^T
    CHOL2(Ssx,128,(i64)0, Lx,256,(i64)128*256+128,
          Ssy,128,(i64)0, Ly,256,(i64)128*256+128);

    // ---- core K = Rx Ry^T = Lx^T Ly ;  A = K K^T ----
    GEMM(Lx,Ly,Km,nullptr, 256,256,256, 256,256,256, 1,0, 1.f,0,0, 1);
    GEMM(Km,Km,Am,nullptr, 256,256,256, 256,256,256, 0,1, 1.f,0,0, 1);

    // ---- EVD of A: tridiag (LDS) -> bisection -> inverse iteration ----
    hipLaunchKernelGGL(fd_tridiag, dim3(1),dim3(256),0,stream, Am,dT,eT,Vh);
    hipLaunchKernelGGL(fd_bisect,  dim3(1),dim3(256),0,stream, dT,eT,lam,wfx,wfy);
    hipLaunchKernelGGL(fd_invit,   dim3(1),dim3(128),0,stream, dT,eT,lam,Ut,iud,iue,iuf);

    // ---- CholQR2 on the 128 top T-basis vectors ----
    GEMM(Ut,Ut,G1q,nullptr, 128,128,256, 128,128,128, 1,0, 1.f,0,0, 1);
    hipLaunchKernelGGL(fd_chol128, dim3(1),dim3(256),0,stream, G1q,128,(i64)0, Ssx,128,(i64)0);
    hipLaunchKernelGGL(fd_trinv128,dim3(1),dim3(128),0,stream, Ssx,128,(i64)0, Xq);
    GEMM(Ut,Xq,Uo1,nullptr, 256,128,128, 128,128,128, 0,0, 1.f,0,0, 1);
    GEMM(Uo1,Uo1,G1q,nullptr, 128,128,256, 128,128,128, 1,0, 1.f,0,0, 1);
    hipLaunchKernelGGL(fd_chol128, dim3(1),dim3(256),0,stream, G1q,128,(i64)0, Ssx,128,(i64)0);
    hipLaunchKernelGGL(fd_trinv128,dim3(1),dim3(128),0,stream, Ssx,128,(i64)0, Xq);
    GEMM(Uo1,Xq,Uo,nullptr, 256,128,128, 128,128,128, 0,0, 1.f,0,0, 1);

    // ---- back-transform to original basis: Ub = Q_H * Uo ----
    hipLaunchKernelGGL(fd_applyq, dim3(4),dim3(256),0,stream, Vh,Uo,Ub);

    // ---- coefficient updates (all GEMMs, no triangular solves) ----
    GEMM(Km,Ub,Pm,nullptr, 256,128,256, 256,128,128, 1,0, 1.f,0,0, 1);   // P = K^T U
    hipLaunchKernelGGL(fd_colscale, dim3(128),dim3(256),0,stream, Pm,wfx,Pf,256);
    hipLaunchKernelGGL(fd_colscale, dim3(128),dim3(256),0,stream, Ub,wfy,Uf,256);
    GEMM(Ly,Pf,Mx,nullptr, 256,128,256, 256,128,128, 0,0, 1.f,0,0, 1);   // Mx = Ry^T P diag
    GEMM(Lx,Uf,My,nullptr, 256,128,256, 256,128,128, 0,0, 1.f,0,0, 1);   // My = Rx^T U diag

    GEMM(Cx,Mx,Bx,nullptr, 8192,128,256, 256,128,128, 0,0, 1.f,0,0, 1);  // Bx' = Cx Mx
    GEMM(Cy,My,By,nullptr, 5120,128,256, 256,128,128, 0,0, 1.f,0,0, 1);  // By' = Cy My
  }

  // ---- final: out = Bx By^T + bias (overwrites all of d_out) ----
  GEMM(Bx,By,out,bias, 8192,5120,128, 128,128,5120, 0,1, 1.f,0,0, 1);
}

// Round 2
// 47779.102 us; speedup vs baseline: 1.3549x; 1.0294x over previous
//
#include <hip/hip_runtime.h>
#include <math.h>

typedef long long i64;

// ---------------------------------------------------------------------------
// Reduction helpers
// ---------------------------------------------------------------------------
__device__ __forceinline__ float waveReduceSum(float v){
#pragma unroll
  for(int o=32;o>0;o>>=1) v += __shfl_down(v,o,64);
  return v;
}
__device__ __forceinline__ float waveReduceMin(float v){
#pragma unroll
  for(int o=32;o>0;o>>=1) v = fminf(v, __shfl_down(v,o,64));
  return v;
}
__device__ __forceinline__ float waveReduceMax(float v){
#pragma unroll
  for(int o=32;o>0;o>>=1) v = fmaxf(v, __shfl_down(v,o,64));
  return v;
}
__device__ __forceinline__ float blockReduceSum256(float val, float* red){
  __syncthreads();
  val = waveReduceSum(val);
  if((threadIdx.x&63)==0) red[threadIdx.x>>6]=val;
  __syncthreads();
  return red[0]+red[1]+red[2]+red[3];
}
__device__ __forceinline__ float blockReduceMin256(float val, float* red){
  __syncthreads();
  val = waveReduceMin(val);
  if((threadIdx.x&63)==0) red[threadIdx.x>>6]=val;
  __syncthreads();
  return fminf(fminf(red[0],red[1]),fminf(red[2],red[3]));
}
__device__ __forceinline__ float blockReduceMax256(float val, float* red){
  __syncthreads();
  val = waveReduceMax(val);
  if((threadIdx.x&63)==0) red[threadIdx.x>>6]=val;
  __syncthreads();
  return fmaxf(fmaxf(red[0],red[1]),fmaxf(red[2],red[3]));
}
__device__ __forceinline__ float blockReduceSum1024(float val, float* red){
  __syncthreads();
  val = waveReduceSum(val);
  if((threadIdx.x&63)==0) red[threadIdx.x>>6]=val;
  __syncthreads();
  float s=0.f;
#pragma unroll
  for(int i=0;i<16;i++) s+=red[i];
  return s;
}

// ---------------------------------------------------------------------------
// Generic strided 2D copy
// ---------------------------------------------------------------------------
__global__ __launch_bounds__(256) void fd_copyblk(
    float* __restrict__ dst, int dld, i64 doff,
    const float* __restrict__ src, int sld, i64 soff,
    int rows, int cols)
{
  i64 tot = (i64)rows*cols;
  for(i64 id = (i64)blockIdx.x*256 + threadIdx.x; id < tot; id += (i64)gridDim.x*256){
    int r = (int)(id / cols), c = (int)(id % cols);
    dst[doff + (i64)r*dld + c] = src[soff + (i64)r*sld + c];
  }
}

// ---------------------------------------------------------------------------
// Generic fp32 GEMM: C = alpha*op(A)op(B) [*csc col-scale] [+C] [+bias]
// ---------------------------------------------------------------------------
__global__ __launch_bounds__(256) void fd_gemm(
    const float* __restrict__ A, const float* __restrict__ B,
    float* __restrict__ C, const float* __restrict__ bias,
    const float* __restrict__ csc,
    int M, int N, int K, int lda, int ldb, int ldc,
    int tA, int tB, float alpha, int betaone, int useAtomic)
{
  __shared__ float As[16][68];
  __shared__ float Bs[16][68];
  int bm = blockIdx.x*64, bn = blockIdx.y*64;
  int kchunk = K / gridDim.z;
  int k0 = blockIdx.z * kchunk;
  int tn = threadIdx.x & 15, tm = threadIdx.x >> 4;
  float acc[4][4] = {{0.f}};
  for(int kt = k0; kt < k0 + kchunk; kt += 16){
    if(tA){
      for(int l=threadIdx.x; l<1024; l+=256){ int kk=l>>6, mm=l&63;
        As[kk][mm] = A[(i64)(kt+kk)*lda + bm+mm]; }
    }else{
      for(int l=threadIdx.x; l<1024; l+=256){ int mm=l>>4, kk=l&15;
        As[kk][mm] = A[(i64)(bm+mm)*lda + kt+kk]; }
    }
    if(tB){
      for(int l=threadIdx.x; l<1024; l+=256){ int nn=l>>4, kk=l&15;
        Bs[kk][nn] = B[(i64)(bn+nn)*ldb + kt+kk]; }
    }else{
      for(int l=threadIdx.x; l<1024; l+=256){ int kk=l>>6, nn=l&63;
        Bs[kk][nn] = B[(i64)(kt+kk)*ldb + bn+nn]; }
    }
    __syncthreads();
#pragma unroll
    for(int kk=0; kk<16; kk++){
      float a[4], b[4];
#pragma unroll
      for(int i=0;i<4;i++){ a[i]=As[kk][tm*4+i]; b[i]=Bs[kk][tn*4+i]; }
#pragma unroll
      for(int i=0;i<4;i++)
#pragma unroll
        for(int j=0;j<4;j++) acc[i][j] += a[i]*b[j];
    }
    __syncthreads();
  }
#pragma unroll
  for(int i=0;i<4;i++){
    int row = bm + tm*4 + i;
#pragma unroll
    for(int j=0;j<4;j++){
      int col = bn + tn*4 + j;
      i64 idx = (i64)row*ldc + col;
      float v = alpha*acc[i][j];
      if(useAtomic){ atomicAdd(&C[idx], v); }
      else{
        if(csc)     v *= csc[col];
        if(betaone) v += C[idx];
        if(bias)    v += bias[col];
        C[idx] = v;
      }
    }
  }
}

// ---------------------------------------------------------------------------
// Cholesky of a 128x128 SPD block (packed-lower in LDS), regularized.
// v2: element-parallel rank-1 update (balanced, pipelined LDS ops) and an
// optional FUSED triangular inverse X=(L^T)^{-1} solved entirely in LDS.
// ---------------------------------------------------------------------------
__device__ __forceinline__ void chol128_body(
    const float* __restrict__ G, int gld, i64 goff,
    float* __restrict__ Lg, int lld, i64 loff,
    float* __restrict__ X,
    float* P, float* colv, float* sc, float* Xs)
{
  int t = threadIdx.x;
  int ln = t & 63, wv = t >> 6;
  for(int i=wv;i<128;i+=4){
    int base = (i*(i+1))>>1;
    for(int j=ln;j<=i;j+=64) P[base+j] = G[goff + (i64)i*gld + j];
  }
  __syncthreads();
  if(t==0){
    float m=0.f;
    for(int i=0;i<128;i++){ float dd=P[((i*(i+1))>>1)+i]; if(dd>m) m=dd; }
    if(!(m>0.f)) m = 1e-20f;
    sc[0] = m*4e-6f;   // diagonal regularization
    sc[1] = m*1e-8f;   // pivot floor
  }
  __syncthreads();
  float reg = sc[0], flo = sc[1];
  if(t<128) P[((t*(t+1))>>1)+t] += reg;
  __syncthreads();
  for(int j=0;j<128;j++){
    if(t==0){
      int jb=(j*(j+1))>>1;
      float dd = fmaxf(P[jb+j], flo);
      float piv = sqrtf(dd);
      P[jb+j] = piv;
      colv[j] = piv;
    }
    __syncthreads();
    float pr = 1.f/colv[j];
    int i = j+1+t;
    if(i<128){
      int base=(i*(i+1))>>1;
      float val = P[base+j]*pr;
      P[base+j] = val;
      colv[i] = val;
    }
    __syncthreads();
    int s = 127-j;
    int E = (s*(s+1))>>1;
    for(int f=t; f<E; f+=256){
      int rr = (int)((sqrtf(8.f*(float)f + 1.f) - 1.f)*0.5f);
      while(((rr*(rr+1))>>1) > f) rr--;
      while((((rr+1)*(rr+2))>>1) <= f) rr++;
      int cc = f - ((rr*(rr+1))>>1);
      int i2 = j+1+rr, k2 = j+1+cc;
      P[((i2*(i2+1))>>1) + k2] -= colv[i2]*colv[k2];
    }
    __syncthreads();
  }
  for(int i=wv;i<128;i+=4){
    int base=(i*(i+1))>>1;
    for(int j=ln;j<128;j+=64)
      Lg[loff + (i64)i*lld + j] = (j<=i)? P[base+j] : 0.f;
  }
  if(X){
    __syncthreads();
    if(t<128){
      int k=t;
      Xs[k*129+k] = 1.f/P[((k*(k+1))>>1)+k];
      for(int i2=k-1;i2>=0;i2--){
        float s2=0.f;
        for(int jj=i2+1;jj<=k;jj++) s2 += P[((jj*(jj+1))>>1)+i2]*Xs[jj*129+k];
        Xs[i2*129+k] = -s2/P[((i2*(i2+1))>>1)+i2];
      }
    }
    __syncthreads();
    for(int idx=t; idx<16384; idx+=256){
      int i2=idx>>7, jj=idx&127;
      X[idx] = (jj>=i2)? Xs[i2*129+jj] : 0.f;
    }
  }
}

__global__ __launch_bounds__(256) void fd_chol128(
    const float* __restrict__ G, int gld, i64 goff,
    float* __restrict__ Lg, int lld, i64 loff, float* __restrict__ X)
{
  __shared__ float P[8256];
  __shared__ float colv[128];
  __shared__ float sc[2];
  __shared__ float Xs[16512];
  chol128_body(G,gld,goff,Lg,lld,loff,X,P,colv,sc,Xs);
}

__global__ __launch_bounds__(256) void fd_chol128x2(
    const float* __restrict__ Ga, int glda, i64 goffa,
    float* __restrict__ La, int llda, i64 loffa, float* __restrict__ Xa,
    const float* __restrict__ Gb, int gldb, i64 goffb,
    float* __restrict__ Lb, int lldb, i64 loffb, float* __restrict__ Xb)
{
  __shared__ float P[8256];
  __shared__ float colv[128];
  __shared__ float sc[2];
  __shared__ float Xs[16512];
  if(blockIdx.x==0) chol128_body(Ga,glda,goffa,La,llda,loffa,Xa,P,colv,sc,Xs);
  else              chol128_body(Gb,gldb,goffb,Lb,lldb,loffb,Xb,P,colv,sc,Xs);
}

// ---------------------------------------------------------------------------
// Householder tridiagonalization of symmetric 256x256 A, fully in LDS.
// v3: 1024 threads (16 waves). Column pass wave-split 16 ways; row-dot and
// rank-2 update split 4 sub-threads per row (stride-4 over float4 blocks).
// Packed-lower rows on 16B-aligned zero-padded bases (pads stay 0).
// ---------------------------------------------------------------------------
__device__ __forceinline__ int rb4(int i){ int a=i>>2; return (a+1)*(2*a+(i&3)); }

__global__ __launch_bounds__(1024) void fd_tridiag(
    const float* __restrict__ A, float* __restrict__ dT,
    float* __restrict__ eT, float* __restrict__ Vh)
{
  const int n = 256;
  __shared__ __align__(16) float P[33280];     // 133.1 KB padded packed lower
  __shared__ __align__(16) float v[256];
  __shared__ __align__(16) float w[256];
  __shared__ __align__(16) float colp[4096];   // 16 waves x 256 col partials
  __shared__ __align__(16) float rp[1024];     // 4 subs x 256 row partials
  __shared__ float red[16];
  int t = threadIdx.x;
  int L = t & 63, wv = t >> 6;    // lane, wave 0..15
  int r = t & 255, sub = t >> 8;  // row, sub-thread 0..3
  for(int idx=t; idx<33280; idx+=1024) P[idx] = 0.f;   // pads must stay 0
  __syncthreads();
  for(int i=wv;i<n;i+=16){
    int base = rb4(i)<<2;
    for(int j=L;j<=i;j+=64) P[base+j] = A[(i64)i*n + j];
  }
  __syncthreads();
  int b4r = rb4(r);
  int br  = b4r<<2;
  const float4* P4  = (const float4*)P;
  float4*       P4w = (float4*)P;
  const float4* V4  = (const float4*)v;
  const float4* W4  = (const float4*)w;
  float4*       C4  = (float4*)colp;
  int c0 = L<<2;

  for(int j=0;j<n-2;j++){
    float xi = (sub==0 && r>j)? P[br + j] : 0.f;
    float nrm2 = blockReduceSum1024(xi*xi, red);
    float x0 = P[(rb4(j+1)<<2) + j];            // broadcast
    float nr = sqrtf(nrm2);
    float beta = (x0>=0.f)? -nr : nr;
    float vn2 = 2.f*nrm2 - 2.f*beta*x0;
    float vs = (vn2>1e-30f)? rsqrtf(vn2) : 0.f;
    if(t==0) eT[j] = beta;
    float vt = 0.f;
    if(sub==0){
      vt = (r>j)? (xi - ((r==j+1)? beta : 0.f))*vs : 0.f;
      v[r] = vt;
      Vh[(i64)j*n + r] = vt;
    }
    __syncthreads();           // v ready

    // ---- u = A2 v ----
    // column partials: u[c] += P[k][c]*v[k], k>c  (16-wave split over k)
    float uc0=0.f, uc1=0.f, uc2=0.f, uc3=0.f;
#pragma unroll 2
    for(int k=j+1+wv; k<n; k+=16){
      float4 q = P4[rb4(k) + L];        // garbage beyond row masked below
      float vk = v[k];
      uc0 += (c0+0 < k)? q.x*vk : 0.f;
      uc1 += (c0+1 < k)? q.y*vk : 0.f;
      uc2 += (c0+2 < k)? q.z*vk : 0.f;
      uc3 += (c0+3 < k)? q.w*vk : 0.f;
    }
    C4[(wv<<6) + L] = make_float4(uc0,uc1,uc2,uc3);
    // row partials: u[r] += P[r][k]*v[k], k<=r  (4-sub stride-4 over blocks)
    int qa = (j+1)>>2;
    float4 acc = make_float4(0.f,0.f,0.f,0.f);
    if(r>j){
      int qe = r>>2;
#pragma unroll 2
      for(int q=qa+sub; q<=qe; q+=4){
        float4 pq = P4[b4r + q];
        float4 vq = V4[q];
        acc.x += pq.x*vq.x; acc.y += pq.y*vq.y;
        acc.z += pq.z*vq.z; acc.w += pq.w*vq.w;
      }
    }
    rp[(sub<<8) + r] = acc.x+acc.y+acc.z+acc.w;
    __syncthreads();           // partials ready
    float ut = 0.f;
    if(sub==0 && r>j){
      float s1=0.f;
#pragma unroll
      for(int i=0;i<16;i++) s1 += colp[(i<<8)+r];
#pragma unroll
      for(int i=0;i<4;i++)  s1 += rp[(i<<8)+r];
      ut = s1;
    }
    float gamma = blockReduceSum1024(vt*ut, red);
    float wt = 2.f*ut - 2.f*gamma*vt;
    if(sub==0) w[r] = wt;
    __syncthreads();           // w ready
    if(r>j){
      float vr, wr;
      if(sub==0){ vr=vt; wr=wt; }
      else      { vr=v[r]; wr=w[r]; }
      int qv = (r>=3)? ((r-3)>>2) : -1;
      if(qv < qa) qv = qa-1;
#pragma unroll 2
      for(int q=qa+sub; q<=qv; q+=4){
        float4 pq = P4[b4r + q];
        float4 vq = V4[q];
        float4 wq = W4[q];
        pq.x -= vr*wq.x + wr*vq.x;
        pq.y -= vr*wq.y + wr*vq.y;
        pq.z -= vr*wq.z + wr*vq.z;
        pq.w -= vr*wq.w + wr*vq.w;
        P4w[b4r + q] = pq;
      }
      if(sub==0){
        int ks = (qv+1)<<2; if(ks < j+1) ks = j+1;
        for(int k=ks; k<=r; ++k) P[br+k] -= vr*w[k] + wr*v[k];
      }
    }
    __syncthreads();           // update done (next xi read depends on it)
  }
  if(sub==0) dT[r] = P[br + r];
  if(t==0) eT[n-2] = P[(rb4(n-1)<<2) + (n-2)];
  if(t==1) eT[n-1] = 0.f;
}

// ---------------------------------------------------------------------------
// Bisection eigenvalues of tridiagonal T: lam[k] = k-th LARGEST, k=0..128.
// ---------------------------------------------------------------------------
__global__ __launch_bounds__(256) void fd_bisect(
    const float* __restrict__ dT, const float* __restrict__ eT,
    float* __restrict__ lam, float* __restrict__ wfx, float* __restrict__ wfy)
{
  __shared__ float d[256], e2[256], eabs[256];
  __shared__ float red[8];
  __shared__ float sgl, sgh, spm, sdel;
  int t = threadIdx.x;
  d[t] = dT[t];
  float ev = (t<255)? eT[t] : 0.f;
  e2[t] = ev*ev; eabs[t] = fabsf(ev);
  __syncthreads();
  float rr = ((t>0)? eabs[t-1] : 0.f) + eabs[t];
  float mn = blockReduceMin256(d[t]-rr, red);
  float mx = blockReduceMax256(d[t]+rr, red);
  if(t==0){
    sgl = mn; sgh = mx;
    float s = fmaxf(fabsf(mn), fabsf(mx));
    spm = fmaxf(1e-25f, 1e-12f*s);
  }
  __syncthreads();
  float glo=sgl, ghi=sgh, pivmin=spm;
  if(t<=128){
    int k = t;
    float lo=glo, hi=ghi;
    for(int it=0; it<34; it++){
      float mid = 0.5f*(lo+hi);
      int cnt=0;
      float q = d[0]-mid; if(q<0.f) cnt++;
      for(int i=1;i<256;i++){
        if(fabsf(q)<pivmin) q = -pivmin;
        q = (d[i]-mid) - e2[i-1]*__builtin_amdgcn_rcpf(q);
        if(q<0.f) cnt++;
      }
      if(cnt <= 255-k) lo=mid; else hi=mid;
    }
    lam[k] = lo;
  }
  __syncthreads();
  if(t==0) sdel = sqrtf(fmaxf(lam[128], 0.f));
  __syncthreads();
  if(t<128){
    float l = lam[t];
    float sg = sqrtf(fmaxf(l,0.f));
    float s2 = fmaxf(sg - sdel, 0.f);
    float s = sqrtf(s2);
    wfx[t] = (s2>0.f && l >1e-30f)? (s/l)  : 0.f;
    wfy[t] = (s2>0.f && sg>1e-30f)? (s/sg) : 0.f;
  }
}

// ---------------------------------------------------------------------------
// Inverse iteration (2 passes) for top-128 eigenvectors of tridiagonal T.
// ---------------------------------------------------------------------------
__global__ __launch_bounds__(128) void fd_invit(
    const float* __restrict__ dT, const float* __restrict__ eT,
    const float* __restrict__ lam, float* __restrict__ Ut,
    float* __restrict__ ud, float* __restrict__ ue, float* __restrict__ uf)
{
  __shared__ float d[256], e[256];
  int k = threadIdx.x;
  for(int i=k;i<256;i+=128){ d[i]=dT[i]; e[i]=(i<255)? eT[i] : 0.f; }
  __syncthreads();
  float scl = fmaxf(fabsf(lam[0]), 1e-20f);
  unsigned hh = (unsigned)k*2654435761u; hh ^= hh>>13; hh *= 1103515245u; hh ^= hh>>16;
  float pert = (float)(hh & 0xFFFFu) * (1.f/65536.f);
  float shift = lam[k] - scl*6e-7f*(0.25f + pert);
  float pivmin = 3e-7f*scl + 1e-30f;
#define AT(a,i) a[(i64)(i)*128 + k]
  for(int i=0;i<256;i++){
    unsigned z = ((unsigned)i*73856093u) ^ ((unsigned)k*19349663u);
    z ^= z>>13; z *= 2654435769u; z ^= z>>16;
    AT(Ut,i) = ((float)(z & 0xFFFFFFu) * (1.f/8388608.f)) - 1.f;
  }
  for(int pass=0; pass<2; pass++){
    float p = d[0]-shift, q = e[0], r = 0.f;
    for(int i=0;i<255;i++){
      float bel = e[i];
      float bn  = d[i+1]-shift;
      float cn  = (i+1<255)? e[i+1] : 0.f;
      float xi  = AT(Ut,i), xn = AT(Ut,i+1);
      if(fabsf(p) >= fabsf(bel)){
        float piv = (fabsf(p)<pivmin)? ((p<0.f)?-pivmin:pivmin) : p;
        float m = bel/piv;
        AT(ud,i)=piv; AT(ue,i)=q; AT(uf,i)=r;
        p = bn - m*q; q = cn - m*r; r = 0.f;
        AT(Ut,i+1) = xn - m*xi;
      } else {
        float piv = bel;
        float m = p/piv;
        AT(ud,i)=piv; AT(ue,i)=bn; AT(uf,i)=cn;
        p = q - m*bn; q = r - m*cn; r = 0.f;
        AT(Ut,i) = xn;
        AT(Ut,i+1) = xi - m*xn;
      }
    }
    {
      float piv = (fabsf(p)<pivmin)? ((p<0.f)?-pivmin:pivmin) : p;
      AT(ud,255)=piv;
    }
    float x1=0.f, x2=0.f, nrm2=0.f;
    for(int i=255;i>=0;i--){
      float s = AT(Ut,i);
      if(i<255) s -= AT(ue,i)*x1;
      if(i<254) s -= AT(uf,i)*x2;
      float x = s / AT(ud,i);
      x = fminf(fmaxf(x, -1e17f), 1e17f);
      AT(Ut,i) = x;
      x2=x1; x1=x;
      nrm2 += x*x;
    }
    float rn = rsqrtf(fmaxf(nrm2, 1e-30f));
    for(int i=0;i<256;i++) AT(Ut,i) *= rn;
  }
#undef AT
}

// ---------------------------------------------------------------------------
// Back-transform: Uout = Q * Uin, Q = H_0 ... H_253 (apply j=253..0).
// v2: redundant reduce by all threads (one less barrier, no idle groups).
// ---------------------------------------------------------------------------
__global__ __launch_bounds__(256) void fd_applyq(
    const float* __restrict__ Vh, const float* __restrict__ Uin,
    float* __restrict__ Uout)
{
  __shared__ float S[256][33];
  __shared__ float v[256];
  __shared__ float part[8][32];
  int c = threadIdx.x & 31, g = threadIdx.x >> 5;   // 8 row-groups of 32
  int cb = blockIdx.x*32;
  for(int i=g*32; i<g*32+32; i++) S[i][c] = Uin[(i64)i*128 + cb + c];
  __syncthreads();
  for(int j=253;j>=0;j--){
    v[threadIdx.x] = Vh[(i64)j*256 + threadIdx.x];
    __syncthreads();
    float pd = 0.f;
#pragma unroll
    for(int i=g*32;i<g*32+32;i++) pd += v[i]*S[i][c];
    part[g][c] = pd;
    __syncthreads();
    float s=0.f;
#pragma unroll
    for(int gg=0;gg<8;gg++) s += part[gg][c];
    float wv2 = 2.f*s;
#pragma unroll
    for(int i=g*32;i<g*32+32;i++) S[i][c] -= v[i]*wv2;
    __syncthreads();
  }
  for(int i=g*32;i<g*32+32;i++) Uout[(i64)i*128 + cb + c] = S[i][c];
}

// ---------------------------------------------------------------------------
// Host driver
// ---------------------------------------------------------------------------
extern "C" void kernel_launch(void* const* d_in, const int* in_sizes, int n_in,
                              void* d_out, int out_size, void* d_ws, size_t ws_size,
                              hipStream_t stream)
{
  const float* x    = (const float*)d_in[0];   // 8192 x 1280
  const float* wgt  = (const float*)d_in[1];   // 5120 x 1280
  const float* bias = (const float*)d_in[2];   // 5120
  float* out = (float*)d_out;

  const int m = 8192, p = 5120, ldx = 1280, nb = 10;

  // ---- scratch layout: everything dead-before-final lives inside d_out ----
  float* ob = (float*)d_out;
  i64 o = 0;
  float* Cx  = ob+o; o += (i64)m*256;
  float* Cy  = ob+o; o += (i64)p*256;
  float* Gxx = ob+o; o += 65536;
  float* Gyy = ob+o; o += 65536;
  float* Lx  = ob+o; o += 65536;
  float* Ly  = ob+o; o += 65536;
  float* Km  = ob+o; o += 65536;
  float* Am  = ob+o; o += 65536;
  float* Vh  = ob+o; o += 65536;
  float* Ssx = ob+o; o += 16384;
  float* Ssy = ob+o; o += 16384;
  float* Xx  = ob+o; o += 16384;
  float* Xy  = ob+o; o += 16384;
  float* Xq  = ob+o; o += 16384;
  float* G1q = ob+o; o += 16384;
  float* dT  = ob+o; o += 256;
  float* eT  = ob+o; o += 256;
  float* lam = ob+o; o += 256;
  float* wfx = ob+o; o += 128;
  float* wfy = ob+o; o += 128;
  float* Ut  = ob+o; o += 32768;
  float* Uo1 = ob+o; o += 32768;
  float* Uo  = ob+o; o += 32768;
  float* Ub  = ob+o; o += 32768;
  float* Pm  = ob+o; o += 32768;
  float* Mx  = ob+o; o += 32768;
  float* My  = ob+o; o += 32768;
  float* iud = ob+o; o += 32768;
  float* iue = ob+o; o += 32768;
  float* iuf = ob+o; o += 32768;

  // Bx/By must survive into the final GEMM (which overwrites d_out) -> d_ws
  float* ws = (float*)d_ws;
  float* Bx = ws;                       // 8192 x 128
  float* By = ws + (i64)m*128;          // 5120 x 128
  (void)ws_size; (void)out_size; (void)n_in; (void)in_sizes;

  auto GEMM = [&](const float* A, const float* B, float* C, const float* bs,
                  const float* cs,
                  int M,int N,int K,int lda,int ldb,int ldc,int tA,int tB,
                  float alpha,int betaone,int atom,int kz){
    dim3 g(M/64, N/64, kz);
    hipLaunchKernelGGL(fd_gemm, g, dim3(256), 0, stream,
                       A,B,C,bs,cs,M,N,K,lda,ldb,ldc,tA,tB,alpha,betaone,atom);
  };
  auto COPY = [&](float* dst,int dld,i64 doff,const float* src,int sld,i64 soff,
                  int rows,int cols){
    i64 tot=(i64)rows*cols; int g=(int)((tot+255)/256); if(g>4096) g=4096;
    hipLaunchKernelGGL(fd_copyblk, dim3(g), dim3(256), 0, stream,
                       dst,dld,doff,src,sld,soff,rows,cols);
  };
  auto Z = [&](float* ptr, i64 elems){ hipMemsetAsync(ptr, 0, (size_t)elems*4, stream); };
  auto CHOL2 = [&](const float* Ga,int glda,i64 goffa, float* La,int llda,i64 loffa, float* Xa,
                   const float* Gb,int gldb,i64 goffb, float* Lb,int lldb,i64 loffb, float* Xb){
    hipLaunchKernelGGL(fd_chol128x2, dim3(2), dim3(256), 0, stream,
                       Ga,glda,goffa,La,llda,loffa,Xa, Gb,gldb,goffb,Lb,lldb,loffb,Xb);
  };

  for(int t=1;t<nb;t++){
    // ---- pack Cx = [Bx | x_t], Cy = [By | w_t] (step 1: Bx=x_0, By=w_0) ----
    if(t==1){ COPY(Cx,256,0, x,  ldx,0, m,128); COPY(Cy,256,0, wgt,ldx,0, p,128); }
    else    { COPY(Cx,256,0, Bx, 128,0, m,128); COPY(Cy,256,0, By, 128,0, p,128); }
    COPY(Cx,256,128, x,  ldx,(i64)t*128, m,128);
    COPY(Cy,256,128, wgt,ldx,(i64)t*128, p,128);

    // ---- Grams (split-K + atomics) ----
    Z(Gxx,65536); Z(Gyy,65536);
    GEMM(Cx,Cx,Gxx,nullptr,nullptr, 256,256,8192, 256,256,256, 1,0, 1.f,0,1, 8);
    GEMM(Cy,Cy,Gyy,nullptr,nullptr, 256,256,5120, 256,256,256, 1,0, 1.f,0,1, 5);

    // ---- blocked 256-Cholesky, x & y sides batched; trinv fused in chol ----
    Z(Lx,65536); Z(Ly,65536);
    CHOL2(Gxx,256,(i64)0, Lx,256,(i64)0, Xx,
          Gyy,256,(i64)0, Ly,256,(i64)0, Xy);
    GEMM(Gxx + (i64)128*256, Xx, Lx + (i64)128*256, nullptr,nullptr,
         128,128,128, 256,128,256, 0,0, 1.f,0,0, 1);                 // L21x
    GEMM(Gyy + (i64)128*256, Xy, Ly + (i64)128*256, nullptr,nullptr,
         128,128,128, 256,128,256, 0,0, 1.f,0,0, 1);                 // L21y
    COPY(Ssx,128,0, Gxx,256,(i64)128*256+128, 128,128);              // Sx = G22x
    COPY(Ssy,128,0, Gyy,256,(i64)128*256+128, 128,128);              // Sy = G22y
    GEMM(Lx + (i64)128*256, Lx + (i64)128*256, Ssx, nullptr,nullptr,
         128,128,128, 256,256,128, 0,1, -1.f,1,0, 1);                // Sx -= L21x L21x^T
    GEMM(Ly + (i64)128*256, Ly + (i64)128*256, Ssy, nullptr,nullptr,
         128,128,128, 256,256,128, 0,1, -1.f,1,0, 1);                // Sy -= L21y L21y^T
    CHOL2(Ssx,128,(i64)0, Lx,256,(i64)128*256+128, nullptr,
          Ssy,128,(i64)0, Ly,256,(i64)128*256+128, nullptr);

    // ---- core K = Rx Ry^T = Lx^T Ly ;  A = K K^T ----
    GEMM(Lx,Ly,Km,nullptr,nullptr, 256,256,256, 256,256,256, 1,0, 1.f,0,0, 1);
    GEMM(Km,Km,Am,nullptr,nullptr, 256,256,256, 256,256,256, 0,1, 1.f,0,0, 1);

    // ---- EVD of A: tridiag (LDS) -> bisection -> inverse iteration ----
    hipLaunchKernelGGL(fd_tridiag, dim3(1),dim3(1024),0,stream, Am,dT,eT,Vh);
    hipLaunchKernelGGL(fd_bisect,  dim3(1),dim3(256),0,stream, dT,eT,lam,wfx,wfy);
    hipLaunchKernelGGL(fd_invit,   dim3(1),dim3(128),0,stream, dT,eT,lam,Ut,iud,iue,iuf);

    // ---- CholQR2 on the 128 top T-basis vectors (trinv fused) ----
    GEMM(Ut,Ut,G1q,nullptr,nullptr, 128,128,256, 128,128,128, 1,0, 1.f,0,0, 1);
    hipLaunchKernelGGL(fd_chol128, dim3(1),dim3(256),0,stream, G1q,128,(i64)0, Ssx,128,(i64)0, Xq);
    GEMM(Ut,Xq,Uo1,nullptr,nullptr, 256,128,128, 128,128,128, 0,0, 1.f,0,0, 1);
    GEMM(Uo1,Uo1,G1q,nullptr,nullptr, 128,128,256, 128,128,128, 1,0, 1.f,0,0, 1);
    hipLaunchKernelGGL(fd_chol128, dim3(1),dim3(256),0,stream, G1q,128,(i64)0, Ssx,128,(i64)0, Xq);
    GEMM(Uo1,Xq,Uo,nullptr,nullptr, 256,128,128, 128,128,128, 0,0, 1.f,0,0, 1);

    // ---- back-transform to original basis: Ub = Q_H * Uo ----
    hipLaunchKernelGGL(fd_applyq, dim3(4),dim3(256),0,stream, Vh,Uo,Ub);

    // ---- coefficient updates (colscale fused into GEMM epilogues) ----
    GEMM(Km,Ub,Pm,nullptr,nullptr, 256,128,256, 256,128,128, 1,0, 1.f,0,0, 1);  // P = K^T U
    GEMM(Ly,Pm,Mx,nullptr,wfx,    256,128,256, 256,128,128, 0,0, 1.f,0,0, 1);  // Mx = (Ry^T P) diag(wfx)
    GEMM(Lx,Ub,My,nullptr,wfy,    256,128,256, 256,128,128, 0,0, 1.f,0,0, 1);  // My = (Rx^T U) diag(wfy)

    GEMM(Cx,Mx,Bx,nullptr,nullptr, 8192,128,256, 256,128,128, 0,0, 1.f,0,0, 1); // Bx' = Cx Mx
    GEMM(Cy,My,By,nullptr,nullptr, 5120,128,256, 256,128,128, 0,0, 1.f,0,0, 1); // By' = Cy My
  }

  // ---- final: out = Bx By^T + bias (overwrites all of d_out) ----
  GEMM(Bx,By,out,bias,nullptr, 8192,5120,128, 128,128,5120, 0,1, 1.f,0,0, 1);
}

// Round 3
// 45691.241 us; speedup vs baseline: 1.4168x; 1.0457x over previous
//
#include <hip/hip_runtime.h>
#include <math.h>

typedef long long i64;

// ---------------------------------------------------------------------------
// Reduction helpers (1024-thread block = 16 waves)
// ---------------------------------------------------------------------------
__device__ __forceinline__ float waveReduceSum(float v){
#pragma unroll
  for(int o=32;o>0;o>>=1) v += __shfl_down(v,o,64);
  return v;
}
__device__ __forceinline__ float waveReduceMin(float v){
#pragma unroll
  for(int o=32;o>0;o>>=1) v = fminf(v, __shfl_down(v,o,64));
  return v;
}
__device__ __forceinline__ float waveReduceMax(float v){
#pragma unroll
  for(int o=32;o>0;o>>=1) v = fmaxf(v, __shfl_down(v,o,64));
  return v;
}
__device__ __forceinline__ float blockReduceSum1024(float val, float* red){
  __syncthreads();
  val = waveReduceSum(val);
  if((threadIdx.x&63)==0) red[threadIdx.x>>6]=val;
  __syncthreads();
  float s=0.f;
#pragma unroll
  for(int i=0;i<16;i++) s+=red[i];
  return s;
}
__device__ __forceinline__ float blockReduceMin1024(float val, float* red){
  __syncthreads();
  val = waveReduceMin(val);
  if((threadIdx.x&63)==0) red[threadIdx.x>>6]=val;
  __syncthreads();
  float s=red[0];
#pragma unroll
  for(int i=1;i<16;i++) s=fminf(s,red[i]);
  return s;
}
__device__ __forceinline__ float blockReduceMax1024(float val, float* red){
  __syncthreads();
  val = waveReduceMax(val);
  if((threadIdx.x&63)==0) red[threadIdx.x>>6]=val;
  __syncthreads();
  float s=red[0];
#pragma unroll
  for(int i=1;i<16;i++) s=fmaxf(s,red[i]);
  return s;
}

// ---------------------------------------------------------------------------
// Pack kernel: Cx=[left|xblk], Cy=[left|wblk], and zero Gxx/Gyy.
// ---------------------------------------------------------------------------
__global__ __launch_bounds__(256) void fd_pack(
    float* __restrict__ Cx, float* __restrict__ Cy,
    const float* __restrict__ lx, int lldx,
    const float* __restrict__ ly, int lldy,
    const float* __restrict__ rx, const float* __restrict__ ry,
    float* __restrict__ Gxx, float* __restrict__ Gyy,
    int m, int p)
{
  i64 cxn = (i64)m*256, cyn = (i64)p*256;
  i64 tot = cxn + cyn + 131072;
  for(i64 id = (i64)blockIdx.x*256 + threadIdx.x; id < tot; id += (i64)gridDim.x*256){
    if(id < cxn){
      int r = (int)(id >> 8), c = (int)(id & 255);
      Cx[id] = (c<128)? lx[(i64)r*lldx + c] : rx[(i64)r*1280 + (c-128)];
    } else if(id < cxn+cyn){
      i64 k = id - cxn;
      int r = (int)(k >> 8), c = (int)(k & 255);
      Cy[k] = (c<128)? ly[(i64)r*lldy + c] : ry[(i64)r*1280 + (c-128)];
    } else {
      i64 z = id - cxn - cyn;
      if(z < 65536) Gxx[z] = 0.f; else Gyy[z-65536] = 0.f;
    }
  }
}

// ---------------------------------------------------------------------------
// Generic fp32 GEMM (external, multi-block): C = alpha*op(A)op(B) [+bias]
// ---------------------------------------------------------------------------
__global__ __launch_bounds__(256) void fd_gemm(
    const float* __restrict__ A, const float* __restrict__ B,
    float* __restrict__ C, const float* __restrict__ bias,
    int M, int N, int K, int lda, int ldb, int ldc,
    int tA, int tB, float alpha, int useAtomic)
{
  __shared__ float As[16][68];
  __shared__ float Bs[16][68];
  int bm = blockIdx.x*64, bn = blockIdx.y*64;
  int kchunk = K / gridDim.z;
  int k0 = blockIdx.z * kchunk;
  int tn = threadIdx.x & 15, tm = threadIdx.x >> 4;
  float acc[4][4] = {{0.f}};
  for(int kt = k0; kt < k0 + kchunk; kt += 16){
    if(tA){
      for(int l=threadIdx.x; l<1024; l+=256){ int kk=l>>6, mm=l&63;
        As[kk][mm] = A[(i64)(kt+kk)*lda + bm+mm]; }
    }else{
      for(int l=threadIdx.x; l<1024; l+=256){ int mm=l>>4, kk=l&15;
        As[kk][mm] = A[(i64)(bm+mm)*lda + kt+kk]; }
    }
    if(tB){
      for(int l=threadIdx.x; l<1024; l+=256){ int nn=l>>4, kk=l&15;
        Bs[kk][nn] = B[(i64)(bn+nn)*ldb + kt+kk]; }
    }else{
      for(int l=threadIdx.x; l<1024; l+=256){ int kk=l>>6, nn=l&63;
        Bs[kk][nn] = B[(i64)(kt+kk)*ldb + bn+nn]; }
    }
    __syncthreads();
#pragma unroll
    for(int kk=0; kk<16; kk++){
      float a[4], b[4];
#pragma unroll
      for(int i=0;i<4;i++){ a[i]=As[kk][tm*4+i]; b[i]=Bs[kk][tn*4+i]; }
#pragma unroll
      for(int i=0;i<4;i++)
#pragma unroll
        for(int j=0;j<4;j++) acc[i][j] += a[i]*b[j];
    }
    __syncthreads();
  }
#pragma unroll
  for(int i=0;i<4;i++){
    int row = bm + tm*4 + i;
#pragma unroll
    for(int j=0;j<4;j++){
      int col = bn + tn*4 + j;
      i64 idx = (i64)row*ldc + col;
      float v = alpha*acc[i][j];
      if(useAtomic){ atomicAdd(&C[idx], v); }
      else{
        if(bias) v += bias[col];
        C[idx] = v;
      }
    }
  }
}

// ===========================================================================
// MEGACHAIN: the entire per-iteration small-matrix chain in ONE kernel.
// 1024 threads, 1 block. LDS arena 38928 floats (155.7 KB), phase-scoped.
// ===========================================================================

// ---- in-block GEMM: 4 teams of 256, each one 64x64 tile, shared barriers ---
// C = alpha*op(A)op(B) [+Dinit] [*csc]; A,B,C,Dinit,csc global.
__device__ void gemm1024(const float* __restrict__ A, const float* __restrict__ B,
    float* __restrict__ C, const float* __restrict__ Dinit, int ldd,
    const float* __restrict__ csc,
    int M,int N,int K,int lda,int ldb,int ldc,int tA,int tB,float alpha,
    float* SMEM)
{
  int t = threadIdx.x; int team = t>>8, tt = t&255;
  float (*As)[68] = (float(*)[68])(SMEM + team*2176);
  float (*Bs)[68] = (float(*)[68])(SMEM + team*2176 + 1088);
  int tn = tt & 15, tm = tt >> 4;
  int tilesN = N>>6;
  int nt = (M>>6)*tilesN;
  int ntp = (nt+3)&~3;
  for(int tile=team; tile<ntp; tile+=4){
    bool act = tile < nt;
    int bm = act? (tile/tilesN)<<6 : 0;
    int bn = act? (tile%tilesN)<<6 : 0;
    float acc[4][4] = {{0.f}};
    for(int kt=0; kt<K; kt+=16){
      if(act){
        if(tA){
          for(int l=tt; l<1024; l+=256){ int kk=l>>6, mm=l&63;
            As[kk][mm] = A[(i64)(kt+kk)*lda + bm+mm]; }
        }else{
          for(int l=tt; l<1024; l+=256){ int mm=l>>4, kk=l&15;
            As[kk][mm] = A[(i64)(bm+mm)*lda + kt+kk]; }
        }
        if(tB){
          for(int l=tt; l<1024; l+=256){ int nn=l>>4, kk=l&15;
            Bs[kk][nn] = B[(i64)(bn+nn)*ldb + kt+kk]; }
        }else{
          for(int l=tt; l<1024; l+=256){ int kk=l>>6, nn=l&63;
            Bs[kk][nn] = B[(i64)(kt+kk)*ldb + bn+nn]; }
        }
      }
      __syncthreads();
      if(act){
#pragma unroll
        for(int kk=0; kk<16; kk++){
          float a[4], b[4];
#pragma unroll
          for(int i=0;i<4;i++){ a[i]=As[kk][tm*4+i]; b[i]=Bs[kk][tn*4+i]; }
#pragma unroll
          for(int i=0;i<4;i++)
#pragma unroll
            for(int j=0;j<4;j++) acc[i][j] += a[i]*b[j];
        }
      }
      __syncthreads();
    }
    if(act){
#pragma unroll
      for(int i=0;i<4;i++){
        int row = bm + tm*4 + i;
#pragma unroll
        for(int j=0;j<4;j++){
          int col = bn + tn*4 + j;
          float v = alpha*acc[i][j];
          if(csc)   v *= csc[col];
          if(Dinit) v += Dinit[(i64)row*ldd + col];
          C[(i64)row*ldc + col] = v;
        }
      }
    }
  }
  __syncthreads();
}

// ---- dual-side 128x128 Cholesky (left-looking, dense LDS) + opt trinv -----
// D: 2x16896 LDS ([128][132] per side); colv 256; scs 8; rp 1024.
// Side s loads G_s, factors, stores L block to Lst_s at (lro,lco), and if
// X_s != null computes X = (L^T)^{-1} to global (ld 128).
__device__ void chol_tri(const float* G0, int gld0, const float* G1, int gld1,
    float* Lst0, float* Lst1, int lro, int lco,
    float* X0, float* X1,
    float* D, float* colv, float* scs, float* rp)
{
  int t = threadIdx.x;
  int s = t>>9, tl = t&511;
  const float* G = s? G1 : G0; int gld = s? gld1 : gld0;
  bool act = (s==0) || (G1 != nullptr);
  float* Ds = D + s*16896;
  if(act){
    for(int l=tl; l<16384; l+=512){ int i=l>>7, j=l&127;
      Ds[i*132+j] = G[(i64)i*gld + j]; }
  }
  __syncthreads();
  if(act && tl==0){
    float mx=0.f;
    for(int i=0;i<128;i++){ float dd=Ds[i*132+i]; if(dd>mx) mx=dd; }
    if(!(mx>0.f)) mx = 1e-20f;
    scs[s*2]   = mx*4e-6f;
    scs[s*2+1] = mx*1e-8f;
  }
  __syncthreads();
  if(act && tl<128) Ds[tl*132+tl] += scs[s*2];
  __syncthreads();
  float flo = scs[s*2+1];
  int i = tl & 127, sub = tl >> 7;
  const float4* D4 = (const float4*)Ds;
  for(int j=0;j<128;j++){
    float pd = 0.f;
    if(act){
      int full = j>>2;
      for(int q=sub; q<full; q+=4){
        float4 a = D4[i*33+q], b = D4[j*33+q];
        pd += a.x*b.x + a.y*b.y + a.z*b.z + a.w*b.w;
      }
      if(sub==0){
        for(int k=(full<<2); k<j; k++) pd += Ds[i*132+k]*Ds[j*132+k];
      }
    }
    rp[(s<<9)+(sub<<7)+i] = pd;
    __syncthreads();
    if(act && sub==0 && i>=j){
      float tmp = Ds[i*132+j]
        - (rp[(s<<9)+i] + rp[(s<<9)+128+i] + rp[(s<<9)+256+i] + rp[(s<<9)+384+i]);
      colv[(s<<7)+i] = tmp;
    }
    __syncthreads();
    if(act && sub==0 && i>=j){
      float dj = fmaxf(colv[(s<<7)+j], flo);
      float piv = sqrtf(dj);
      Ds[i*132+j] = (i==j)? piv : colv[(s<<7)+i]/piv;
    }
    __syncthreads();
  }
  // store L block (lower + zero upper within the 128x128 block)
  {
    float* Lst = s? Lst1 : Lst0;
    if(act && Lst){
      for(int l=tl; l<16384; l+=512){ int r=l>>7, c=l&127;
        Lst[(i64)(lro+r)*256 + lco+c] = (c<=r)? Ds[r*132+c] : 0.f; }
    }
  }
  __syncthreads();
  // fused trinv: X = (L^T)^{-1}, one thread per column, X in strict upper of Ds
  if(X0){
    if(t<256){
      int c = t&127, s2 = t>>7;
      bool a2 = (s2==0) || (X1 != nullptr);
      if(a2){
        float* Dd = D + s2*16896;
        float* Xo = s2? X1 : X0;
        float xc = 1.f/Dd[c*132+c];
        Xo[(i64)c*128 + c] = xc;
        for(int r=c+1;r<128;r++) Xo[(i64)r*128+c] = 0.f;
        for(int r=c-1;r>=0;r--){
          float sum = Dd[c*132+r]*xc;
          for(int jj=r+1;jj<c;jj++) sum += Dd[jj*132+r]*Dd[jj*132+c];
          float xv = -sum/Dd[r*132+r];
          Dd[r*132+c] = xv;          // strict upper (own column, own thread)
          Xo[(i64)r*128+c] = xv;
        }
      }
    }
    __syncthreads();
  }
}

// ---- tridiagonalization phase (v3 logic on carved LDS) --------------------
__device__ __forceinline__ int rb4(int i){ int a=i>>2; return (a+1)*(2*a+(i&3)); }

__device__ void tridiag_dev(const float* __restrict__ A, float* __restrict__ dT,
    float* __restrict__ eT, float* __restrict__ Vh, float* LDSF)
{
  const int n = 256;
  float* P    = LDSF;            // 33280
  float* tv   = LDSF + 33280;    // 256
  float* tw   = LDSF + 33536;    // 256
  float* colp = LDSF + 33792;    // 4096
  float* trp  = LDSF + 37888;    // 1024
  float* red  = LDSF + 38912;    // 16
  int t = threadIdx.x;
  int L = t & 63, wv = t >> 6;
  int r = t & 255, sub = t >> 8;
  for(int idx=t; idx<33280; idx+=1024) P[idx] = 0.f;
  __syncthreads();
  for(int i=wv;i<n;i+=16){
    int base = rb4(i)<<2;
    for(int j=L;j<=i;j+=64) P[base+j] = A[(i64)i*n + j];
  }
  __syncthreads();
  int b4r = rb4(r);
  int br  = b4r<<2;
  const float4* P4  = (const float4*)P;
  float4*       P4w = (float4*)P;
  const float4* V4  = (const float4*)tv;
  const float4* W4  = (const float4*)tw;
  float4*       C4  = (float4*)colp;
  int c0 = L<<2;

  for(int j=0;j<n-2;j++){
    float xi = (sub==0 && r>j)? P[br + j] : 0.f;
    float nrm2 = blockReduceSum1024(xi*xi, red);
    float x0 = P[(rb4(j+1)<<2) + j];
    float nr = sqrtf(nrm2);
    float beta = (x0>=0.f)? -nr : nr;
    float vn2 = 2.f*nrm2 - 2.f*beta*x0;
    float vs = (vn2>1e-30f)? rsqrtf(vn2) : 0.f;
    if(t==0) eT[j] = beta;
    float vt = 0.f;
    if(sub==0){
      vt = (r>j)? (xi - ((r==j+1)? beta : 0.f))*vs : 0.f;
      tv[r] = vt;
      Vh[(i64)j*n + r] = vt;
    }
    __syncthreads();
    float uc0=0.f, uc1=0.f, uc2=0.f, uc3=0.f;
#pragma unroll 2
    for(int k=j+1+wv; k<n; k+=16){
      float4 q = P4[rb4(k) + L];
      float vk = tv[k];
      uc0 += (c0+0 < k)? q.x*vk : 0.f;
      uc1 += (c0+1 < k)? q.y*vk : 0.f;
      uc2 += (c0+2 < k)? q.z*vk : 0.f;
      uc3 += (c0+3 < k)? q.w*vk : 0.f;
    }
    C4[(wv<<6) + L] = make_float4(uc0,uc1,uc2,uc3);
    int qa = (j+1)>>2;
    float4 acc = make_float4(0.f,0.f,0.f,0.f);
    if(r>j){
      int qe = r>>2;
#pragma unroll 2
      for(int q=qa+sub; q<=qe; q+=4){
        float4 pq = P4[b4r + q];
        float4 vq = V4[q];
        acc.x += pq.x*vq.x; acc.y += pq.y*vq.y;
        acc.z += pq.z*vq.z; acc.w += pq.w*vq.w;
      }
    }
    trp[(sub<<8) + r] = acc.x+acc.y+acc.z+acc.w;
    __syncthreads();
    float ut = 0.f;
    if(sub==0 && r>j){
      float s1=0.f;
#pragma unroll
      for(int i=0;i<16;i++) s1 += colp[(i<<8)+r];
#pragma unroll
      for(int i=0;i<4;i++)  s1 += trp[(i<<8)+r];
      ut = s1;
    }
    float gamma = blockReduceSum1024(vt*ut, red);
    float wt = 2.f*ut - 2.f*gamma*vt;
    if(sub==0) tw[r] = wt;
    __syncthreads();
    if(r>j){
      float vr, wr;
      if(sub==0){ vr=vt; wr=wt; }
      else      { vr=tv[r]; wr=tw[r]; }
      int qv = (r>=3)? ((r-3)>>2) : -1;
      if(qv < qa) qv = qa-1;
#pragma unroll 2
      for(int q=qa+sub; q<=qv; q+=4){
        float4 pq = P4[b4r + q];
        float4 vq = V4[q];
        float4 wq = W4[q];
        pq.x -= vr*wq.x + wr*vq.x;
        pq.y -= vr*wq.y + wr*vq.y;
        pq.z -= vr*wq.z + wr*vq.z;
        pq.w -= vr*wq.w + wr*vq.w;
        P4w[b4r + q] = pq;
      }
      if(sub==0){
        int ks = (qv+1)<<2; if(ks < j+1) ks = j+1;
        for(int k=ks; k<=r; ++k) P[br+k] -= vr*tw[k] + wr*tv[k];
      }
    }
    __syncthreads();
  }
  if(sub==0) dT[r] = P[br + r];
  if(t==0) eT[n-2] = P[(rb4(n-1)<<2) + (n-2)];
  if(t==1) eT[n-1] = 0.f;
  __syncthreads();
}

// ---------------------------------------------------------------------------
__global__ __launch_bounds__(1024) void fd_chain(
    const float* __restrict__ Gxx, const float* __restrict__ Gyy,
    float* __restrict__ Lx, float* __restrict__ Ly,
    float* __restrict__ Xx, float* __restrict__ Xy, float* __restrict__ Xq,
    float* __restrict__ Sgx, float* __restrict__ Sgy, float* __restrict__ G1q,
    float* __restrict__ Km, float* __restrict__ Am, float* __restrict__ Vh,
    float* __restrict__ dT, float* __restrict__ eT, float* __restrict__ lam,
    float* __restrict__ wfx, float* __restrict__ wfy,
    float* __restrict__ Ut, float* __restrict__ Uo1, float* __restrict__ Uo,
    float* __restrict__ Ub, float* __restrict__ Pm,
    float* __restrict__ Mx, float* __restrict__ My,
    float* __restrict__ iud, float* __restrict__ iue, float* __restrict__ iuf)
{
  static __shared__ float LDSF[38928];   // 155.7 KB arena, phase-scoped
  int t = threadIdx.x;
  float* red = LDSF + 38912;

  // carve aliases
  float* CD   = LDSF;              // chol dense 2x16896
  float* Ccol = LDSF + 33792;      // 256
  float* Cscs = LDSF + 34048;      // 8
  float* Crp  = LDSF + 34056;      // 1024

  // ===== Phase A: 256-level blocked Cholesky, both sides =====
  // zero upper-right blocks Lx/Ly[0:128][128:256]
  for(int l=t; l<32768; l+=1024){
    int mt = l>>14, r = (l>>7)&127, c = l&127;
    (mt? Ly : Lx)[(i64)r*256 + 128 + c] = 0.f;
  }
  __syncthreads();
  // G11 chol + trinv (dual)
  chol_tri(Gxx,256, Gyy,256, Lx,Ly, 0,0, Xx,Xy, CD,Ccol,Cscs,Crp);
  // L21 = G21 * X11 (per side)
  gemm1024(Gxx + (i64)128*256, Xx, Lx + (i64)128*256, nullptr,0, nullptr,
           128,128,128, 256,128,256, 0,0, 1.f, LDSF);
  gemm1024(Gyy + (i64)128*256, Xy, Ly + (i64)128*256, nullptr,0, nullptr,
           128,128,128, 256,128,256, 0,0, 1.f, LDSF);
  // S = G22 - L21 L21^T
  gemm1024(Lx + (i64)128*256, Lx + (i64)128*256, Sgx,
           Gxx + (i64)128*256 + 128, 256, nullptr,
           128,128,128, 256,256,128, 0,1, -1.f, LDSF);
  gemm1024(Ly + (i64)128*256, Ly + (i64)128*256, Sgy,
           Gyy + (i64)128*256 + 128, 256, nullptr,
           128,128,128, 256,256,128, 0,1, -1.f, LDSF);
  // L22 chol (dual, no trinv)
  chol_tri(Sgx,128, Sgy,128, Lx,Ly, 128,128, nullptr,nullptr, CD,Ccol,Cscs,Crp);

  // ===== Phase B: Km = Lx^T Ly ; Am = Km Km^T =====
  gemm1024(Lx,Ly,Km, nullptr,0,nullptr, 256,256,256, 256,256,256, 1,0, 1.f, LDSF);
  gemm1024(Km,Km,Am, nullptr,0,nullptr, 256,256,256, 256,256,256, 0,1, 1.f, LDSF);

  // ===== Phase C: tridiagonalization =====
  tridiag_dev(Am, dT, eT, Vh, LDSF);

  // ===== Phase D: bisection eigenvalues + shrink weights =====
  {
    float* bd = LDSF;        // 256
    float* be2 = LDSF+256;   // 256
    float* bea = LDSF+512;   // 256
    float* bsc = LDSF+768;   // 4: gl, gh, pm, del
    if(t<256){
      bd[t] = dT[t];
      float ev = (t<255)? eT[t] : 0.f;
      be2[t] = ev*ev; bea[t] = fabsf(ev);
    }
    __syncthreads();
    float vmn =  1e30f, vmx = -1e30f;
    if(t<256){
      float rr = ((t>0)? bea[t-1] : 0.f) + bea[t];
      vmn = bd[t]-rr; vmx = bd[t]+rr;
    }
    float mn = blockReduceMin1024(vmn, red);
    float mx = blockReduceMax1024(vmx, red);
    if(t==0){
      bsc[0]=mn; bsc[1]=mx;
      float s = fmaxf(fabsf(mn), fabsf(mx));
      bsc[2] = fmaxf(1e-25f, 1e-12f*s);
    }
    __syncthreads();
    float glo=bsc[0], ghi=bsc[1], pivmin=bsc[2];
    if(t<=128){
      int k = t;
      float lo=glo, hi=ghi;
      for(int it=0; it<34; it++){
        float mid = 0.5f*(lo+hi);
        int cnt=0;
        float q = bd[0]-mid; if(q<0.f) cnt++;
        for(int i=1;i<256;i++){
          if(fabsf(q)<pivmin) q = -pivmin;
          q = (bd[i]-mid) - be2[i-1]*__builtin_amdgcn_rcpf(q);
          if(q<0.f) cnt++;
        }
        if(cnt <= 255-k) lo=mid; else hi=mid;
      }
      lam[k] = lo;
    }
    __syncthreads();
    if(t==0) bsc[3] = sqrtf(fmaxf(lam[128], 0.f));
    __syncthreads();
    if(t<128){
      float l = lam[t];
      float sg = sqrtf(fmaxf(l,0.f));
      float s2 = fmaxf(sg - bsc[3], 0.f);
      float s = sqrtf(s2);
      wfx[t] = (s2>0.f && l >1e-30f)? (s/l)  : 0.f;
      wfy[t] = (s2>0.f && sg>1e-30f)? (s/sg) : 0.f;
    }
    __syncthreads();
  }

  // ===== Phase E: inverse iteration, Ut in LDS =====
  {
    float* Utl = LDSF;         // 32768 ([256][128])
    float* dd  = LDSF+32768;   // 256
    float* ee  = LDSF+33024;   // 256
    if(t<256){ dd[t]=dT[t]; ee[t]=(t<255)? eT[t] : 0.f; }
    __syncthreads();
    if(t<128){
      int k = t;
      float scl = fmaxf(fabsf(lam[0]), 1e-20f);
      unsigned hh = (unsigned)k*2654435761u; hh ^= hh>>13; hh *= 1103515245u; hh ^= hh>>16;
      float pert = (float)(hh & 0xFFFFu) * (1.f/65536.f);
      float shift = lam[k] - scl*6e-7f*(0.25f + pert);
      float pivmin = 3e-7f*scl + 1e-30f;
#define UT(i) Utl[(i)*128 + k]
#define GA(a,i) a[(i64)(i)*128 + k]
      for(int i=0;i<256;i++){
        unsigned z = ((unsigned)i*73856093u) ^ ((unsigned)k*19349663u);
        z ^= z>>13; z *= 2654435769u; z ^= z>>16;
        UT(i) = ((float)(z & 0xFFFFFFu) * (1.f/8388608.f)) - 1.f;
      }
      for(int pass=0; pass<2; pass++){
        float p = dd[0]-shift, q = ee[0], r = 0.f;
        for(int i=0;i<255;i++){
          float bel = ee[i];
          float bn  = dd[i+1]-shift;
          float cn  = (i+1<255)? ee[i+1] : 0.f;
          float xi  = UT(i), xn = UT(i+1);
          if(fabsf(p) >= fabsf(bel)){
            float piv = (fabsf(p)<pivmin)? ((p<0.f)?-pivmin:pivmin) : p;
            float mfac = bel/piv;
            GA(iud,i)=piv; GA(iue,i)=q; GA(iuf,i)=r;
            p = bn - mfac*q; q = cn - mfac*r; r = 0.f;
            UT(i+1) = xn - mfac*xi;
          } else {
            float piv = bel;
            float mfac = p/piv;
            GA(iud,i)=piv; GA(iue,i)=bn; GA(iuf,i)=cn;
            p = q - mfac*bn; q = r - mfac*cn; r = 0.f;
            UT(i) = xn;
            UT(i+1) = xi - mfac*xn;
          }
        }
        {
          float piv = (fabsf(p)<pivmin)? ((p<0.f)?-pivmin:pivmin) : p;
          GA(iud,255)=piv;
        }
        float x1=0.f, x2=0.f, nrm2=0.f;
        for(int i=255;i>=0;i--){
          float s = UT(i);
          if(i<255) s -= GA(iue,i)*x1;
          if(i<254) s -= GA(iuf,i)*x2;
          float x = s / GA(iud,i);
          x = fminf(fmaxf(x, -1e17f), 1e17f);
          UT(i) = x;
          x2=x1; x1=x;
          nrm2 += x*x;
        }
        float rn = rsqrtf(fmaxf(nrm2, 1e-30f));
        for(int i=0;i<256;i++) UT(i) *= rn;
      }
#undef UT
#undef GA
    }
    __syncthreads();
    for(int l=t; l<32768; l+=1024) Ut[l] = Utl[l];
    __syncthreads();
  }

  // ===== Phase F: CholQR2 =====
  gemm1024(Ut,Ut,G1q, nullptr,0,nullptr, 128,128,256, 128,128,128, 1,0, 1.f, LDSF);
  chol_tri(G1q,128, nullptr,0, nullptr,nullptr, 0,0, Xq,nullptr, CD,Ccol,Cscs,Crp);
  gemm1024(Ut,Xq,Uo1, nullptr,0,nullptr, 256,128,128, 128,128,128, 0,0, 1.f, LDSF);
  gemm1024(Uo1,Uo1,G1q, nullptr,0,nullptr, 128,128,256, 128,128,128, 1,0, 1.f, LDSF);
  chol_tri(G1q,128, nullptr,0, nullptr,nullptr, 0,0, Xq,nullptr, CD,Ccol,Cscs,Crp);
  gemm1024(Uo1,Xq,Uo, nullptr,0,nullptr, 256,128,128, 128,128,128, 0,0, 1.f, LDSF);

  // ===== Phase G: back-transform Ub = Q * Uo =====
  {
    float* S    = LDSF;          // [256][132] = 33792
    float* vv   = LDSF+33792;    // 256
    float* part = LDSF+34048;    // 1024
    for(int l=t; l<32768; l+=1024){ int i=l>>7, c=l&127; S[i*132+c] = Uo[l]; }
    __syncthreads();
    int c = t&127, g = t>>7;
    for(int j=253;j>=0;j--){
      if(t<256) vv[t] = Vh[(i64)j*256 + t];
      __syncthreads();
      float pd = 0.f;
#pragma unroll
      for(int r2=0;r2<32;r2++){ int i=g*32+r2; pd += vv[i]*S[i*132+c]; }
      part[g*128+c] = pd;
      __syncthreads();
      float sm=0.f;
#pragma unroll
      for(int gg=0;gg<8;gg++) sm += part[gg*128+c];
      float wv2 = 2.f*sm;
#pragma unroll
      for(int r2=0;r2<32;r2++){ int i=g*32+r2; S[i*132+c] -= vv[i]*wv2; }
      __syncthreads();
    }
    for(int l=t; l<32768; l+=1024){ int i=l>>7, c2=l&127; Ub[l] = S[i*132+c2]; }
    __syncthreads();
  }

  // ===== Phase H: coefficient updates =====
  gemm1024(Km,Ub,Pm, nullptr,0,nullptr, 256,128,256, 256,128,128, 1,0, 1.f, LDSF);
  gemm1024(Ly,Pm,Mx, nullptr,0,wfx,    256,128,256, 256,128,128, 0,0, 1.f, LDSF);
  gemm1024(Lx,Ub,My, nullptr,0,wfy,    256,128,256, 256,128,128, 0,0, 1.f, LDSF);
}

// ---------------------------------------------------------------------------
// Host driver
// ---------------------------------------------------------------------------
extern "C" void kernel_launch(void* const* d_in, const int* in_sizes, int n_in,
                              void* d_out, int out_size, void* d_ws, size_t ws_size,
                              hipStream_t stream)
{
  const float* x    = (const float*)d_in[0];   // 8192 x 1280
  const float* wgt  = (const float*)d_in[1];   // 5120 x 1280
  const float* bias = (const float*)d_in[2];   // 5120
  float* out = (float*)d_out;

  const int m = 8192, p = 5120, nb = 10;

  // ---- scratch layout inside d_out ----
  float* ob = (float*)d_out;
  i64 o = 0;
  float* Cx  = ob+o; o += (i64)m*256;
  float* Cy  = ob+o; o += (i64)p*256;
  float* Gxx = ob+o; o += 65536;
  float* Gyy = ob+o; o += 65536;
  float* Lx  = ob+o; o += 65536;
  float* Ly  = ob+o; o += 65536;
  float* Km  = ob+o; o += 65536;
  float* Am  = ob+o; o += 65536;
  float* Vh  = ob+o; o += 65536;
  float* Sgx = ob+o; o += 16384;
  float* Sgy = ob+o; o += 16384;
  float* Xx  = ob+o; o += 16384;
  float* Xy  = ob+o; o += 16384;
  float* Xq  = ob+o; o += 16384;
  float* G1q = ob+o; o += 16384;
  float* dT  = ob+o; o += 256;
  float* eT  = ob+o; o += 256;
  float* lam = ob+o; o += 256;
  float* wfx = ob+o; o += 128;
  float* wfy = ob+o; o += 128;
  float* Ut  = ob+o; o += 32768;
  float* Uo1 = ob+o; o += 32768;
  float* Uo  = ob+o; o += 32768;
  float* Ub  = ob+o; o += 32768;
  float* Pm  = ob+o; o += 32768;
  float* Mx  = ob+o; o += 32768;
  float* My  = ob+o; o += 32768;
  float* iud = ob+o; o += 32768;
  float* iue = ob+o; o += 32768;
  float* iuf = ob+o; o += 32768;

  float* ws = (float*)d_ws;
  float* Bx = ws;                       // 8192 x 128
  float* By = ws + (i64)m*128;          // 5120 x 128
  (void)ws_size; (void)out_size; (void)n_in; (void)in_sizes;

  auto GEMM = [&](const float* A, const float* B, float* C, const float* bs,
                  int M,int N,int K,int lda,int ldb,int ldc,int tA,int tB,
                  float alpha,int atom,int kz){
    dim3 g(M/64, N/64, kz);
    hipLaunchKernelGGL(fd_gemm, g, dim3(256), 0, stream,
                       A,B,C,bs,M,N,K,lda,ldb,ldc,tA,tB,alpha,atom);
  };

  for(int t=1;t<nb;t++){
    const float* lx = (t==1)? x   : Bx;  int lldx = (t==1)? 1280 : 128;
    const float* ly = (t==1)? wgt : By;  int lldy = (t==1)? 1280 : 128;
    hipLaunchKernelGGL(fd_pack, dim3(4096), dim3(256), 0, stream,
                       Cx, Cy, lx, lldx, ly, lldy,
                       x + (i64)t*128, wgt + (i64)t*128, Gxx, Gyy, m, p);

    GEMM(Cx,Cx,Gxx,nullptr, 256,256,8192, 256,256,256, 1,0, 1.f,1, 8);
    GEMM(Cy,Cy,Gyy,nullptr, 256,256,5120, 256,256,256, 1,0, 1.f,1, 5);

    hipLaunchKernelGGL(fd_chain, dim3(1), dim3(1024), 0, stream,
                       Gxx,Gyy,Lx,Ly,Xx,Xy,Xq,Sgx,Sgy,G1q,
                       Km,Am,Vh,dT,eT,lam,wfx,wfy,
                       Ut,Uo1,Uo,Ub,Pm,Mx,My,iud,iue,iuf);

    GEMM(Cx,Mx,Bx,nullptr, 8192,128,256, 256,128,128, 0,0, 1.f,0, 1);
    GEMM(Cy,My,By,nullptr, 5120,128,256, 256,128,128, 0,0, 1.f,0, 1);
  }

  GEMM(Bx,By,out,bias, 8192,5120,128, 128,128,5120, 0,1, 1.f,0, 1);
}